// Round 8
// baseline (282.676 us; speedup 1.0000x reference)
//
#include <hip/hip_runtime.h>

#define BATCH   2
#define SEQ     2048
#define DMODEL  1024
#define NHEADS  16
#define DHEAD   64
#define NGROUPS 8
#define NTOK    (BATCH * SEQ)   // 4096
#define QKV_N   2048            // 1024 Q | 512 K | 512 V

typedef unsigned short ushort_t;
typedef unsigned int u32;
typedef __attribute__((ext_vector_type(8))) short short8;
typedef __attribute__((ext_vector_type(4))) float f32x4;
typedef __attribute__((ext_vector_type(16))) float f32x16;

#define MFMA16(a, b, c) __builtin_amdgcn_mfma_f32_16x16x32_bf16((a), (b), (c), 0, 0, 0)
#define MFMA32(a, b, c) __builtin_amdgcn_mfma_f32_32x32x16_bf16((a), (b), (c), 0, 0, 0)

// async global->LDS, 16B per lane, LDS dest = wave-uniform base + lane*16
#define GLOAD16(gp, lp)                                                        \
    __builtin_amdgcn_global_load_lds(                                          \
        (const u32 __attribute__((address_space(1)))*)(gp),                    \
        (u32 __attribute__((address_space(3)))*)(lp), 16, 0, 0)

__device__ __forceinline__ ushort_t f2bu(float x) {
    unsigned u = __builtin_bit_cast(unsigned, x);
    unsigned r = (u + 0x7fffu + ((u >> 16) & 1u)) >> 16;   // RNE
    return (ushort_t)r;
}

// ---------------------------------------------------------------------------
// Prep 1: resid f32 -> bf16
// ---------------------------------------------------------------------------
__global__ __launch_bounds__(256) void cvt_resid(
    const float* __restrict__ in, ushort_t* __restrict__ out)
{
    const int i4 = blockIdx.x * 256 + threadIdx.x;
    union { float4 v; float f[4]; } a;
    a.v = *reinterpret_cast<const float4*>(in + (size_t)i4 * 4);
    union { uint2 v; ushort_t u[4]; } o;
    #pragma unroll
    for (int j = 0; j < 4; ++j) o.u[j] = f2bu(a.f[j]);
    *reinterpret_cast<uint2*>(out + (size_t)i4 * 4) = o.v;
}

// ---------------------------------------------------------------------------
// Prep 2: Wt[n=2048][k=1024] bf16 (n-major) from W_Q|W_K|W_V (f32, k-major)
// ---------------------------------------------------------------------------
__global__ __launch_bounds__(256) void tr_wqkv(
    const float* __restrict__ Wq, const float* __restrict__ Wk,
    const float* __restrict__ Wv, ushort_t* __restrict__ Wt)
{
    __shared__ float Ws[64][65];
    const int t  = threadIdx.x;
    const int k0 = blockIdx.x * 64;
    const int n0 = blockIdx.y * 64;

    const float* src; int stride, boff;
    if (n0 < 1024)       { src = Wq; stride = 1024; boff = n0; }
    else if (n0 < 1536)  { src = Wk; stride = 512;  boff = n0 - 1024; }
    else                 { src = Wv; stride = 512;  boff = n0 - 1536; }

    #pragma unroll
    for (int i = 0; i < 4; ++i) {
        const int c = i * 256 + t;
        const int row = c >> 4, cc = (c & 15) * 4;
        union { float4 v; float f[4]; } a;
        a.v = *reinterpret_cast<const float4*>(src + (size_t)(k0 + row) * stride + boff + cc);
        #pragma unroll
        for (int j = 0; j < 4; ++j) Ws[row][cc + j] = a.f[j];
    }
    __syncthreads();
    #pragma unroll
    for (int i = 0; i < 2; ++i) {
        const int c = i * 256 + t;
        const int nr = c >> 3, kc = (c & 7) * 8;
        union { uint4 v; ushort_t u[8]; } o;
        #pragma unroll
        for (int j = 0; j < 8; ++j) o.u[j] = f2bu(Ws[kc + j][nr]);
        *reinterpret_cast<uint4*>(Wt + (size_t)(n0 + nr) * 1024 + k0 + kc) = o.v;
    }
}

// ---------------------------------------------------------------------------
// Prep 3: Wout_t[d=1024][j=h*64+e] bf16 from W_out[e][h][d] f32
// ---------------------------------------------------------------------------
__global__ __launch_bounds__(256) void tr_wout(
    const float* __restrict__ Wout, ushort_t* __restrict__ Wt)
{
    __shared__ float Ws[64][65];
    const int t  = threadIdx.x;
    const int d0 = blockIdx.x * 64;
    const int h  = blockIdx.y;

    #pragma unroll
    for (int i = 0; i < 4; ++i) {
        const int c = i * 256 + t;
        const int e = c >> 4, dd = (c & 15) * 4;
        union { float4 v; float f[4]; } a;
        a.v = *reinterpret_cast<const float4*>(Wout + (size_t)(e * 16 + h) * 1024 + d0 + dd);
        #pragma unroll
        for (int j = 0; j < 4; ++j) Ws[e][dd + j] = a.f[j];
    }
    __syncthreads();
    #pragma unroll
    for (int i = 0; i < 2; ++i) {
        const int c = i * 256 + t;
        const int dr = c >> 3, ec = (c & 7) * 8;
        union { uint4 v; ushort_t u[8]; } o;
        #pragma unroll
        for (int j = 0; j < 8; ++j) o.u[j] = f2bu(Ws[ec + j][dr]);
        *reinterpret_cast<uint4*>(Wt + (size_t)(d0 + dr) * 1024 + h * 64 + ec) = o.v;
    }
}

// ---------------------------------------------------------------------------
// Prep 4 (after qkv_gemm): Vt[b][g][e][s] bf16 from qkv V slab.
// ---------------------------------------------------------------------------
__global__ __launch_bounds__(256) void tr_v(
    const ushort_t* __restrict__ qkv, ushort_t* __restrict__ Vt)
{
    __shared__ ushort_t T[64][72];
    const int t  = threadIdx.x;
    const int s0 = blockIdx.x * 64;
    const int g  = blockIdx.y;
    const int b  = blockIdx.z;

    #pragma unroll
    for (int i = 0; i < 2; ++i) {
        const int c = i * 256 + t;
        const int row = c >> 3, ec = (c & 7) * 8;
        *reinterpret_cast<uint4*>(&T[row][ec]) =
            *reinterpret_cast<const uint4*>(
                qkv + (size_t)(b * SEQ + s0 + row) * QKV_N + 1536 + g * 64 + ec);
    }
    __syncthreads();
    #pragma unroll
    for (int i = 0; i < 2; ++i) {
        const int c = i * 256 + t;
        const int er = c >> 3, sc = (c & 7) * 8;
        union { uint4 v; ushort_t u[8]; } o;
        #pragma unroll
        for (int j = 0; j < 8; ++j) o.u[j] = T[sc + j][er];
        *reinterpret_cast<uint4*>(
            Vt + (size_t)((b * NGROUPS + g) * 64 + er) * SEQ + s0 + sc) = o.v;
    }
}

// ---------------------------------------------------------------------------
// MFMA GEMM (m97-style): 128x128 tile, BK=32, global_load_lds width 16,
// XOR-swizzled 16B chunks -> <=4-way on fragment reads.
// ---------------------------------------------------------------------------
__global__ __launch_bounds__(256) void qkv_gemm(
    const ushort_t* __restrict__ A, const ushort_t* __restrict__ Bt,
    ushort_t* __restrict__ C)
{
    __shared__ ushort_t As[128][32];
    __shared__ ushort_t Bs[128][32];

    const int t = threadIdx.x;
    const int wave = t >> 6, lane = t & 63;
    const int quad = lane >> 4, x = lane & 15;
    const int wm = (wave >> 1) * 64, wn = (wave & 1) * 64;
    const int m0 = blockIdx.y * 128, n0 = blockIdx.x * 128;

    const int sr = lane >> 2;
    const int gc = (lane & 3) ^ (sr & 3);

    f32x4 acc[4][4];
    #pragma unroll
    for (int i = 0; i < 4; ++i)
        #pragma unroll
        for (int j = 0; j < 4; ++j) acc[i][j] = (f32x4)(0.f);

    const int swz = (quad ^ (x & 3)) * 8;

    for (int k0 = 0; k0 < 1024; k0 += 32) {
        #pragma unroll
        for (int s = 0; s < 2; ++s) {
            const int r0 = (wave * 2 + s) * 16;
            GLOAD16(A  + (size_t)(m0 + r0 + sr) * 1024 + k0 + gc * 8, &As[r0][0]);
            GLOAD16(Bt + (size_t)(n0 + r0 + sr) * 1024 + k0 + gc * 8, &Bs[r0][0]);
        }
        __syncthreads();
        short8 af[4], bf[4];
        #pragma unroll
        for (int mt = 0; mt < 4; ++mt)
            af[mt] = *reinterpret_cast<const short8*>(&As[wm + mt * 16 + x][swz]);
        #pragma unroll
        for (int nt = 0; nt < 4; ++nt)
            bf[nt] = *reinterpret_cast<const short8*>(&Bs[wn + nt * 16 + x][swz]);
        #pragma unroll
        for (int mt = 0; mt < 4; ++mt)
            #pragma unroll
            for (int nt = 0; nt < 4; ++nt)
                acc[mt][nt] = MFMA16(af[mt], bf[nt], acc[mt][nt]);
        __syncthreads();
    }

    #pragma unroll
    for (int mt = 0; mt < 4; ++mt)
        #pragma unroll
        for (int nt = 0; nt < 4; ++nt)
            #pragma unroll
            for (int r = 0; r < 4; ++r) {
                const int row = m0 + wm + mt * 16 + quad * 4 + r;
                const int col = n0 + wn + nt * 16 + x;
                C[(size_t)row * QKV_N + col] = f2bu(acc[mt][nt][r]);
            }
}

__global__ __launch_bounds__(256) void out_gemm(
    const ushort_t* __restrict__ A, const ushort_t* __restrict__ Bt,
    const float* __restrict__ bias, float* __restrict__ C)
{
    __shared__ ushort_t As[128][32];
    __shared__ ushort_t Bs[128][32];

    const int t = threadIdx.x;
    const int wave = t >> 6, lane = t & 63;
    const int quad = lane >> 4, x = lane & 15;
    const int wm = (wave >> 1) * 64, wn = (wave & 1) * 64;
    const int m0 = blockIdx.y * 128, n0 = blockIdx.x * 128;

    const int sr = lane >> 2;
    const int gc = (lane & 3) ^ (sr & 3);

    f32x4 acc[4][4];
    #pragma unroll
    for (int i = 0; i < 4; ++i)
        #pragma unroll
        for (int j = 0; j < 4; ++j) acc[i][j] = (f32x4)(0.f);

    const int swz = (quad ^ (x & 3)) * 8;

    for (int k0 = 0; k0 < 1024; k0 += 32) {
        #pragma unroll
        for (int s = 0; s < 2; ++s) {
            const int r0 = (wave * 2 + s) * 16;
            GLOAD16(A  + (size_t)(m0 + r0 + sr) * 1024 + k0 + gc * 8, &As[r0][0]);
            GLOAD16(Bt + (size_t)(n0 + r0 + sr) * 1024 + k0 + gc * 8, &Bs[r0][0]);
        }
        __syncthreads();
        short8 af[4], bf[4];
        #pragma unroll
        for (int mt = 0; mt < 4; ++mt)
            af[mt] = *reinterpret_cast<const short8*>(&As[wm + mt * 16 + x][swz]);
        #pragma unroll
        for (int nt = 0; nt < 4; ++nt)
            bf[nt] = *reinterpret_cast<const short8*>(&Bs[wn + nt * 16 + x][swz]);
        #pragma unroll
        for (int mt = 0; mt < 4; ++mt)
            #pragma unroll
            for (int nt = 0; nt < 4; ++nt)
                acc[mt][nt] = MFMA16(af[mt], bf[nt], acc[mt][nt]);
        __syncthreads();
    }

    float bv[4];
    #pragma unroll
    for (int nt = 0; nt < 4; ++nt) bv[nt] = bias[n0 + wn + nt * 16 + x];

    #pragma unroll
    for (int mt = 0; mt < 4; ++mt)
        #pragma unroll
        for (int nt = 0; nt < 4; ++nt)
            #pragma unroll
            for (int r = 0; r < 4; ++r) {
                const int row = m0 + wm + mt * 16 + quad * 4 + r;
                const int col = n0 + wn + nt * 16 + x;
                C[(size_t)row * 1024 + col] = acc[mt][nt][r] + bv[nt];
            }
}

// ---------------------------------------------------------------------------
// MFMA flash attention, v7 (= v6 with fixed epilogue normalization):
//  - block = (qt, h, b), 64-row q-tile, 4 waves = 2 row-halves x 2 key-halves
//  - S^T via MFMA32(K, Q); P packed to bf16 in registers, PV A-fragment
//    built with __shfl_xor(.,32) -- no P round-trip through LDS
//  - l routed through LDS indexed by qrow, re-indexed per accumulator reg
//    (v6 bug: applied lane-indexed linv to reg-indexed rows)
// ---------------------------------------------------------------------------
__global__ __launch_bounds__(256, 4) void attn(
    const ushort_t* __restrict__ qkv, const ushort_t* __restrict__ Vt,
    ushort_t* __restrict__ z)
{
    __shared__ ushort_t smem[3 * 64 * 72];   // Qs | Ks | Vts, pitch 72
    ushort_t* Qs  = smem;
    ushort_t* Ks  = smem + 4608;
    ushort_t* Vts = smem + 9216;

    const int t = threadIdx.x;
    const int wave = t >> 6, lane = t & 63;
    const int l5 = lane >> 5, lm = lane & 31;
    const int rh = wave >> 1;            // row half (q-rows rh*32..)
    const int ch = wave & 1;             // key half (keys ch*32..)
    const int qt = (gridDim.x - 1) - blockIdx.x;   // heavy blocks first
    const int h  = blockIdx.y;
    const int b  = blockIdx.z;
    const int g  = h >> 1;
    const int qrow0 = qt * 64;

    const int srow = t >> 3;             // 0..31 staging row (i*32 offset)
    const int sgc  = t & 7;              // staging 16B chunk

    // ---- stage Q ----
    #pragma unroll
    for (int i = 0; i < 2; ++i) {
        const int row = srow + i * 32;
        const int lc = sgc ^ ((row >> 3) & 3);
        *reinterpret_cast<uint4*>(&Qs[row * 72 + lc * 8]) =
            *reinterpret_cast<const uint4*>(
                qkv + (size_t)(b * SEQ + qrow0 + row) * QKV_N + h * DHEAD + sgc * 8);
    }
    __syncthreads();

    // ---- hoist Q B-fragments (n = qrow = rh*32+lm, k = e) ----
    short8 qf[4];
    {
        const int row = rh * 32 + lm;
        const int sw = (row >> 3) & 3;
        #pragma unroll
        for (int ks = 0; ks < 4; ++ks) {
            const int c = (2 * ks + l5) ^ sw;
            qf[ks] = *reinterpret_cast<const short8*>(&Qs[row * 72 + c * 8]);
        }
    }

    f32x16 o0 = (f32x16)(0.f), o1 = (f32x16)(0.f);
    float l_acc = 0.f;

    const ushort_t* kg = qkv + (size_t)b * SEQ * QKV_N + 1024 + g * DHEAD + sgc * 8;
    const ushort_t* vg = Vt + ((size_t)(b * NGROUPS + g) * 64) * SEQ + sgc * 8;

    uint4 kr[2], vr[2];
    #pragma unroll
    for (int i = 0; i < 2; ++i) {
        const int row = srow + i * 32;
        kr[i] = *reinterpret_cast<const uint4*>(kg + (size_t)row * QKV_N);
        vr[i] = *reinterpret_cast<const uint4*>(vg + (size_t)row * SEQ);
    }

    const bool full_skip_diag = (rh == 0) && (ch == 1);  // quarter fully masked on diag
    const int qlocal = rh * 32 + lm;

    for (int kt = 0; kt <= qt; ++kt) {
        __syncthreads();
        #pragma unroll
        for (int i = 0; i < 2; ++i) {
            const int row = srow + i * 32;
            const int lc = sgc ^ ((row >> 3) & 3);
            *reinterpret_cast<uint4*>(&Ks[row * 72 + lc * 8])  = kr[i];
            *reinterpret_cast<uint4*>(&Vts[row * 72 + lc * 8]) = vr[i];
        }
        __syncthreads();

        if (kt < qt) {   // prefetch next K/V tile (overlaps compute)
            #pragma unroll
            for (int i = 0; i < 2; ++i) {
                const int row = srow + i * 32;
                kr[i] = *reinterpret_cast<const uint4*>(
                    kg + (size_t)((kt + 1) * 64 + row) * QKV_N);
                vr[i] = *reinterpret_cast<const uint4*>(
                    vg + (size_t)row * SEQ + (kt + 1) * 64);
            }
        }

        const bool diag = (kt == qt);
        if (diag && full_skip_diag) continue;

        // --- S^T quarter = K[ch*32.., e] . Q[rh*32.., e]^T ---
        f32x16 s = (f32x16)(0.f);
        {
            const int krow = ch * 32 + lm;
            const int swk = (krow >> 3) & 3;
            #pragma unroll
            for (int ks = 0; ks < 4; ++ks) {
                const int c = (2 * ks + l5) ^ swk;
                short8 kf = *reinterpret_cast<const short8*>(&Ks[krow * 72 + c * 8]);
                s = MFMA32(kf, qf[ks], s);
            }
        }

        // --- exp + mask + pack to bf16 pairs (all same q-row = qlocal) ---
        u32 A[8];
        #pragma unroll
        for (int r = 0; r < 8; ++r) {
            float p0 = __expf(s[2 * r] * 0.125f);
            float p1 = __expf(s[2 * r + 1] * 0.125f);
            if (diag) {
                const int key0 = ch * 32 + ((2 * r) & 3) + 8 * (r >> 1) + 4 * l5;
                if (key0 > qlocal)     p0 = 0.f;
                if (key0 + 1 > qlocal) p1 = 0.f;
            }
            l_acc += p0 + p1;
            A[r] = (__builtin_bit_cast(u32, p1) & 0xffff0000u) |
                   (__builtin_bit_cast(u32, p0) >> 16);
        }

        // --- partner exchange (lane^32) -> PV A-fragments ---
        u32 Bx[8];
        #pragma unroll
        for (int r = 0; r < 8; ++r) Bx[r] = __shfl_xor(A[r], 32);

        union { short8 v; u32 u[4]; } ap[2];
        ap[0].u[0] = l5 ? Bx[2] : A[0];
        ap[0].u[1] = l5 ? Bx[3] : A[1];
        ap[0].u[2] = l5 ? A[2]  : Bx[0];
        ap[0].u[3] = l5 ? A[3]  : Bx[1];
        ap[1].u[0] = l5 ? Bx[6] : A[4];
        ap[1].u[1] = l5 ? Bx[7] : A[5];
        ap[1].u[2] = l5 ? A[6]  : Bx[4];
        ap[1].u[3] = l5 ? A[7]  : Bx[5];

        // --- O += P . V  (keys ch*32 + ks2*16 ..) ---
        #pragma unroll
        for (int ks2 = 0; ks2 < 2; ++ks2) {
            const int kc = ch * 4 + ks2 * 2 + l5;   // 16B chunk of key dim
            {
                const int vrow = lm;
                const int c = kc ^ ((vrow >> 3) & 3);
                short8 vf = *reinterpret_cast<const short8*>(&Vts[vrow * 72 + c * 8]);
                o0 = MFMA32(ap[ks2].v, vf, o0);
            }
            {
                const int vrow = 32 + lm;
                const int c = kc ^ ((vrow >> 3) & 3);
                short8 vf = *reinterpret_cast<const short8*>(&Vts[vrow * 72 + c * 8]);
                o1 = MFMA32(ap[ks2].v, vf, o1);
            }
        }
    }

    // ---- epilogue ----
    // l_acc per lane belongs to qrow = rh*32 + lm; o0/o1[r] belong to
    // qrow = rh*32 + (r&3)+8*(r>>2)+4*l5  -> route l through LDS by qrow.
    l_acc += __shfl_xor(l_acc, 32);        // sum this wave's 32-key half

    float* ored   = (float*)smem;          // [128][32] = 16 KB
    float* lred   = (float*)smem + 4096;   // 64 floats (qrow partial, ch=1)
    float* lrecip = (float*)smem + 4224;   // 64 floats (1/l by qrow)
    __syncthreads();                       // all LDS compute reads done
    if (ch == 1) {
        float* dst = ored + (rh * 64 + lane) * 32;
        #pragma unroll
        for (int r = 0; r < 16; ++r) { dst[r] = o0[r]; dst[16 + r] = o1[r]; }
        if (lane < 32) lred[rh * 32 + lane] = l_acc;
    }
    __syncthreads();
    if (ch == 0 && lane < 32)
        lrecip[rh * 32 + lane] = 1.f / (l_acc + lred[rh * 32 + lane]);
    __syncthreads();
    if (ch == 0) {
        const float* src = ored + (rh * 64 + lane) * 32;
        #pragma unroll
        for (int r = 0; r < 16; ++r) {
            const int row_local = (r & 3) + 8 * (r >> 2) + 4 * l5;
            const float inv = lrecip[rh * 32 + row_local];
            const size_t rowbase =
                (size_t)(b * SEQ + qrow0 + rh * 32 + row_local) * 1024 + h * DHEAD;
            z[rowbase + lm]      = f2bu((o0[r] + src[r])      * inv);
            z[rowbase + 32 + lm] = f2bu((o1[r] + src[16 + r]) * inv);
        }
    }
}

// ---------------------------------------------------------------------------
extern "C" void kernel_launch(void* const* d_in, const int* in_sizes, int n_in,
                              void* d_out, int out_size, void* d_ws, size_t ws_size,
                              hipStream_t stream)
{
    const float* resid = (const float*)d_in[0];
    const float* Wq    = (const float*)d_in[1];
    const float* Wk    = (const float*)d_in[2];
    const float* Wv    = (const float*)d_in[3];
    const float* Wout  = (const float*)d_in[4];
    const float* bout  = (const float*)d_in[5];
    float* out = (float*)d_out;

    ushort_t* rbf   = (ushort_t*)d_ws;                       //  8 MB  [4096][1024]
    ushort_t* wqkvt = rbf   + (size_t)NTOK * DMODEL;         //  4 MB  [2048][1024]
    ushort_t* woutt = wqkvt + (size_t)QKV_N * DMODEL;        //  2 MB  [1024][1024]
    ushort_t* qkv   = woutt + (size_t)DMODEL * DMODEL;       // 16 MB  [4096][2048]
    ushort_t* z     = qkv   + (size_t)NTOK * QKV_N;          //  8 MB  [4096][1024]
    ushort_t* vt    = rbf;   // alias: rbf dead after qkv_gemm; tr_v runs later

    cvt_resid<<<dim3(NTOK * DMODEL / 1024), 256, 0, stream>>>(resid, rbf);
    tr_wqkv  <<<dim3(16, 32), 256, 0, stream>>>(Wq, Wk, Wv, wqkvt);
    tr_wout  <<<dim3(16, 16), 256, 0, stream>>>(Wout, woutt);
    qkv_gemm <<<dim3(16, 32), 256, 0, stream>>>(rbf, wqkvt, qkv);
    tr_v     <<<dim3(SEQ / 64, NGROUPS, BATCH), 256, 0, stream>>>(qkv, vt);
    attn     <<<dim3(32, NHEADS, BATCH), 256, 0, stream>>>(qkv, vt, z);
    out_gemm <<<dim3(8, 32), 256, 0, stream>>>(z, woutt, bout, out);
}